// Round 1
// baseline (1408.999 us; speedup 1.0000x reference)
//
#include <hip/hip_runtime.h>
#include <math.h>

// Problem: B=8, T_OUT=2048, T_IN=2048, D=512
//   attn = softmax(output @ context^T)          [B,2048,2048]
//   mix  = attn @ context                        [B,2048,512]
//   out  = tanh([mix, output] @ W^T + b)         [B,2048,512]
// d_out = out (8,388,608 f32) ++ attn (33,554,432 f32)

#define BK 32
#define PAD 68   // 64 + 4: keeps float4 (16B) alignment for LDS rows, <=4-way store aliasing

// ---------------------------------------------------------------------------
// Kernel 1: scores[b, o, i] = sum_d output[b,o,d] * context[b,i,d]
// A and B are both K-contiguous (A @ B^T). 64x64 tile, 4x4 micro-tile.
// ---------------------------------------------------------------------------
__global__ __launch_bounds__(256) void scores_kernel(
    const float* __restrict__ outp, const float* __restrict__ ctx,
    float* __restrict__ attn)
{
    __shared__ float As[BK][PAD];   // As[k][m]
    __shared__ float Bs[BK][PAD];   // Bs[k][n]
    const int b  = blockIdx.z;
    const int oy = blockIdx.y;
    const int ix = blockIdx.x;
    const int tid = threadIdx.x;
    const int tx = tid & 15, ty = tid >> 4;

    const float* Abase = outp + ((size_t)b * 2048 + oy * 64) * 512;
    const float* Bbase = ctx  + ((size_t)b * 2048 + ix * 64) * 512;

    float acc[4][4] = {};

    for (int kk = 0; kk < 512; kk += BK) {
#pragma unroll
        for (int h = 0; h < 2; ++h) {
            const int f   = tid + h * 256;
            const int row = f >> 3;          // 0..63
            const int k4  = f & 7;           // 0..7 (float4 within 32-wide k chunk)
            float4 a = *(const float4*)(Abase + (size_t)row * 512 + kk + k4 * 4);
            float4 c = *(const float4*)(Bbase + (size_t)row * 512 + kk + k4 * 4);
            As[k4 * 4 + 0][row] = a.x; As[k4 * 4 + 1][row] = a.y;
            As[k4 * 4 + 2][row] = a.z; As[k4 * 4 + 3][row] = a.w;
            Bs[k4 * 4 + 0][row] = c.x; Bs[k4 * 4 + 1][row] = c.y;
            Bs[k4 * 4 + 2][row] = c.z; Bs[k4 * 4 + 3][row] = c.w;
        }
        __syncthreads();
#pragma unroll
        for (int k = 0; k < BK; ++k) {
            float4 av = *(const float4*)&As[k][ty * 4];
            float4 bv = *(const float4*)&Bs[k][tx * 4];
            acc[0][0] += av.x * bv.x; acc[0][1] += av.x * bv.y;
            acc[0][2] += av.x * bv.z; acc[0][3] += av.x * bv.w;
            acc[1][0] += av.y * bv.x; acc[1][1] += av.y * bv.y;
            acc[1][2] += av.y * bv.z; acc[1][3] += av.y * bv.w;
            acc[2][0] += av.z * bv.x; acc[2][1] += av.z * bv.y;
            acc[2][2] += av.z * bv.z; acc[2][3] += av.z * bv.w;
            acc[3][0] += av.w * bv.x; acc[3][1] += av.w * bv.y;
            acc[3][2] += av.w * bv.z; acc[3][3] += av.w * bv.w;
        }
        __syncthreads();
    }

    float* dst = attn + ((size_t)b * 2048 + oy * 64 + ty * 4) * 2048 + ix * 64 + tx * 4;
#pragma unroll
    for (int i = 0; i < 4; ++i) {
        float4 v = make_float4(acc[i][0], acc[i][1], acc[i][2], acc[i][3]);
        *(float4*)(dst + (size_t)i * 2048) = v;
    }
}

// ---------------------------------------------------------------------------
// Kernel 2: in-place row softmax over 2048-wide rows (16384 rows total)
// ---------------------------------------------------------------------------
__global__ __launch_bounds__(256) void softmax_kernel(float* __restrict__ attn)
{
    const size_t base = (size_t)blockIdx.x * 2048;
    const int tid = threadIdx.x;
    float4 v0 = *(float4*)(attn + base + tid * 4);
    float4 v1 = *(float4*)(attn + base + 1024 + tid * 4);

    float mx = fmaxf(fmaxf(fmaxf(v0.x, v0.y), fmaxf(v0.z, v0.w)),
                     fmaxf(fmaxf(v1.x, v1.y), fmaxf(v1.z, v1.w)));
#pragma unroll
    for (int off = 32; off > 0; off >>= 1)
        mx = fmaxf(mx, __shfl_down(mx, off));

    __shared__ float red[4];
    const int wave = tid >> 6, lane = tid & 63;
    if (lane == 0) red[wave] = mx;
    __syncthreads();
    if (tid == 0) {
        float m = fmaxf(fmaxf(red[0], red[1]), fmaxf(red[2], red[3]));
        red[0] = m;
    }
    __syncthreads();
    mx = red[0];
    __syncthreads();

    v0.x = expf(v0.x - mx); v0.y = expf(v0.y - mx);
    v0.z = expf(v0.z - mx); v0.w = expf(v0.w - mx);
    v1.x = expf(v1.x - mx); v1.y = expf(v1.y - mx);
    v1.z = expf(v1.z - mx); v1.w = expf(v1.w - mx);

    float s = v0.x + v0.y + v0.z + v0.w + v1.x + v1.y + v1.z + v1.w;
#pragma unroll
    for (int off = 32; off > 0; off >>= 1)
        s += __shfl_down(s, off);
    if (lane == 0) red[wave] = s;
    __syncthreads();
    if (tid == 0) red[0] = red[0] + red[1] + red[2] + red[3];
    __syncthreads();
    const float inv = 1.0f / red[0];

    v0.x *= inv; v0.y *= inv; v0.z *= inv; v0.w *= inv;
    v1.x *= inv; v1.y *= inv; v1.z *= inv; v1.w *= inv;
    *(float4*)(attn + base + tid * 4) = v0;
    *(float4*)(attn + base + 1024 + tid * 4) = v1;
}

// ---------------------------------------------------------------------------
// Kernel 3: mix[b,m,n] = sum_k attn[b,m,k] * context[b,k,n]   (A @ B)
// ---------------------------------------------------------------------------
__global__ __launch_bounds__(256) void pv_kernel(
    const float* __restrict__ attn, const float* __restrict__ ctx,
    float* __restrict__ mix)
{
    __shared__ float As[BK][PAD];   // As[k][m] (transposed)
    __shared__ float Bs[BK][PAD];   // Bs[k][n] (direct)
    const int b  = blockIdx.z;
    const int my = blockIdx.y;
    const int nx = blockIdx.x;
    const int tid = threadIdx.x;
    const int tx = tid & 15, ty = tid >> 4;

    const float* Abase = attn + ((size_t)b * 2048 + my * 64) * 2048;
    const float* Bbase = ctx  + ((size_t)b * 2048) * 512 + nx * 64;

    float acc[4][4] = {};

    for (int kk = 0; kk < 2048; kk += BK) {
#pragma unroll
        for (int h = 0; h < 2; ++h) {
            const int f = tid + h * 256;
            // A: 64 rows x 32 k -> transpose
            const int row = f >> 3, k4 = f & 7;
            float4 a = *(const float4*)(Abase + (size_t)row * 2048 + kk + k4 * 4);
            As[k4 * 4 + 0][row] = a.x; As[k4 * 4 + 1][row] = a.y;
            As[k4 * 4 + 2][row] = a.z; As[k4 * 4 + 3][row] = a.w;
            // B: 32 k-rows x 64 n -> direct
            const int krow = f >> 4, col4 = f & 15;
            float4 c = *(const float4*)(Bbase + (size_t)(kk + krow) * 512 + col4 * 4);
            *(float4*)&Bs[krow][col4 * 4] = c;
        }
        __syncthreads();
#pragma unroll
        for (int k = 0; k < BK; ++k) {
            float4 av = *(const float4*)&As[k][ty * 4];
            float4 bv = *(const float4*)&Bs[k][tx * 4];
            acc[0][0] += av.x * bv.x; acc[0][1] += av.x * bv.y;
            acc[0][2] += av.x * bv.z; acc[0][3] += av.x * bv.w;
            acc[1][0] += av.y * bv.x; acc[1][1] += av.y * bv.y;
            acc[1][2] += av.y * bv.z; acc[1][3] += av.y * bv.w;
            acc[2][0] += av.z * bv.x; acc[2][1] += av.z * bv.y;
            acc[2][2] += av.z * bv.z; acc[2][3] += av.z * bv.w;
            acc[3][0] += av.w * bv.x; acc[3][1] += av.w * bv.y;
            acc[3][2] += av.w * bv.z; acc[3][3] += av.w * bv.w;
        }
        __syncthreads();
    }

    float* dst = mix + ((size_t)b * 2048 + my * 64 + ty * 4) * 512 + nx * 64 + tx * 4;
#pragma unroll
    for (int i = 0; i < 4; ++i) {
        float4 v = make_float4(acc[i][0], acc[i][1], acc[i][2], acc[i][3]);
        *(float4*)(dst + (size_t)i * 512) = v;
    }
}

// ---------------------------------------------------------------------------
// Kernel 4: out[m,n] = tanh(b[n] + sum_c comb[m,c] * W[n,c])
//   comb[m,c] = c<512 ? mix[m*512+c] : output[m*512+c-512]
//   m in [0,16384), n in [0,512), c in [0,1024)
// ---------------------------------------------------------------------------
__global__ __launch_bounds__(256) void linear_kernel(
    const float* __restrict__ mix, const float* __restrict__ outp,
    const float* __restrict__ Wm, const float* __restrict__ bias,
    float* __restrict__ dst)
{
    __shared__ float As[BK][PAD];   // comb transposed: As[k][m]
    __shared__ float Ws[BK][PAD];   // W    transposed: Ws[k][n]
    const int my = blockIdx.y;   // 0..255
    const int nx = blockIdx.x;   // 0..7
    const int tid = threadIdx.x;
    const int tx = tid & 15, ty = tid >> 4;
    const int m0 = my * 64, n0 = nx * 64;

    float acc[4][4] = {};

    for (int kk = 0; kk < 1024; kk += BK) {
        const float* Abase = (kk < 512) ? (mix  + (size_t)m0 * 512 + kk)
                                        : (outp + (size_t)m0 * 512 + (kk - 512));
#pragma unroll
        for (int h = 0; h < 2; ++h) {
            const int f = tid + h * 256;
            const int row = f >> 3, k4 = f & 7;
            float4 a = *(const float4*)(Abase + (size_t)row * 512 + k4 * 4);
            As[k4 * 4 + 0][row] = a.x; As[k4 * 4 + 1][row] = a.y;
            As[k4 * 4 + 2][row] = a.z; As[k4 * 4 + 3][row] = a.w;
            float4 w = *(const float4*)(Wm + (size_t)(n0 + row) * 1024 + kk + k4 * 4);
            Ws[k4 * 4 + 0][row] = w.x; Ws[k4 * 4 + 1][row] = w.y;
            Ws[k4 * 4 + 2][row] = w.z; Ws[k4 * 4 + 3][row] = w.w;
        }
        __syncthreads();
#pragma unroll
        for (int k = 0; k < BK; ++k) {
            float4 av = *(const float4*)&As[k][ty * 4];
            float4 bv = *(const float4*)&Ws[k][tx * 4];
            acc[0][0] += av.x * bv.x; acc[0][1] += av.x * bv.y;
            acc[0][2] += av.x * bv.z; acc[0][3] += av.x * bv.w;
            acc[1][0] += av.y * bv.x; acc[1][1] += av.y * bv.y;
            acc[1][2] += av.y * bv.z; acc[1][3] += av.y * bv.w;
            acc[2][0] += av.z * bv.x; acc[2][1] += av.z * bv.y;
            acc[2][2] += av.z * bv.z; acc[2][3] += av.z * bv.w;
            acc[3][0] += av.w * bv.x; acc[3][1] += av.w * bv.y;
            acc[3][2] += av.w * bv.z; acc[3][3] += av.w * bv.w;
        }
        __syncthreads();
    }

#pragma unroll
    for (int i = 0; i < 4; ++i) {
        const int n = n0 + tx * 4;
        float4 bv = *(const float4*)(bias + n);
        float4 v;
        v.x = tanhf(acc[i][0] + bv.x);
        v.y = tanhf(acc[i][1] + bv.y);
        v.z = tanhf(acc[i][2] + bv.z);
        v.w = tanhf(acc[i][3] + bv.w);
        *(float4*)(dst + (size_t)(m0 + ty * 4 + i) * 512 + n) = v;
    }
}

extern "C" void kernel_launch(void* const* d_in, const int* in_sizes, int n_in,
                              void* d_out, int out_size, void* d_ws, size_t ws_size,
                              hipStream_t stream) {
    const float* outp = (const float*)d_in[0];   // [8,2048,512]
    const float* ctx  = (const float*)d_in[1];   // [8,2048,512]
    const float* Wm   = (const float*)d_in[2];   // [512,1024]
    const float* bias = (const float*)d_in[3];   // [512]

    float* out  = (float*)d_out;                 // [8,2048,512] = 8,388,608
    float* attn = out + (size_t)8 * 2048 * 512;  // [8,2048,2048]
    float* mix  = (float*)d_ws;                  // [8,2048,512] scratch (33.5 MB)

    // 1) raw scores into the attn output region
    scores_kernel<<<dim3(32, 32, 8), 256, 0, stream>>>(outp, ctx, attn);
    // 2) in-place row softmax
    softmax_kernel<<<dim3(16384), 256, 0, stream>>>(attn);
    // 3) mix = attn @ context
    pv_kernel<<<dim3(8, 32, 8), 256, 0, stream>>>(attn, ctx, mix);
    // 4) out = tanh([mix, output] @ W^T + b)
    linear_kernel<<<dim3(8, 256), 256, 0, stream>>>(mix, outp, Wm, bias, out);
}

// Round 2
// 575.175 us; speedup vs baseline: 2.4497x; 2.4497x over previous
//
#include <hip/hip_runtime.h>
#include <math.h>

// B=8, T_OUT=2048, T_IN=2048, D=512
// attn = softmax(outp @ ctx^T); mix = attn @ ctx; out = tanh([mix,outp] @ W^T + b)
// d_out = out (8.4M f32) ++ attn (33.6M f32)
//
// Strategy: bf16 hi/lo split-MFMA emulation of f32 GEMMs (no fp32 MFMA on CDNA4).
//   scores: 3-MFMA split (hh+hl+lh)  — logits need ~f32 accuracy pre-softmax
//   pv:     attn plain bf16 x ctxT split (2 MFMA)
//   linear: full split (3 MFMA) + fused bias+tanh

typedef short s8v __attribute__((ext_vector_type(8)));    // 8 bf16 (4 VGPR)
typedef float f4v __attribute__((ext_vector_type(4)));    // MFMA acc

__device__ __forceinline__ unsigned short f2bf(float f) {
    unsigned int u = __float_as_uint(f);
    u += 0x7fff + ((u >> 16) & 1);           // RNE
    return (unsigned short)(u >> 16);
}
__device__ __forceinline__ float bf2f(unsigned short h) {
    return __uint_as_float(((unsigned int)h) << 16);
}

__device__ __forceinline__ void async16(void* lds, const void* g) {
    __builtin_amdgcn_global_load_lds(
        (const __attribute__((address_space(1))) unsigned int*)g,
        (__attribute__((address_space(3))) unsigned int*)lds, 16, 0, 0);
}

// ---------------------------------------------------------------------------
// Prep: elementwise f32 -> bf16 hi/lo split (one float4 per thread)
// ---------------------------------------------------------------------------
__global__ __launch_bounds__(256) void split_kernel(
    const float* __restrict__ src, unsigned short* __restrict__ hi,
    unsigned short* __restrict__ lo)
{
    const size_t i = ((size_t)blockIdx.x * 256 + threadIdx.x) * 4;
    float4 v = *(const float4*)(src + i);
    ushort4 h, l;
    h.x = f2bf(v.x); l.x = f2bf(v.x - bf2f(h.x));
    h.y = f2bf(v.y); l.y = f2bf(v.y - bf2f(h.y));
    h.z = f2bf(v.z); l.z = f2bf(v.z - bf2f(h.z));
    h.w = f2bf(v.w); l.w = f2bf(v.w - bf2f(h.w));
    *(ushort4*)(hi + i) = h;
    *(ushort4*)(lo + i) = l;
}

// ---------------------------------------------------------------------------
// Prep: ctx[b][i][d] f32 -> ctxT_hi/lo[b][d][i] bf16 (32x32 LDS tile)
// ---------------------------------------------------------------------------
__global__ __launch_bounds__(256) void transpose_split_kernel(
    const float* __restrict__ ctx, unsigned short* __restrict__ tHi,
    unsigned short* __restrict__ tLo)
{
    __shared__ float tile[32][33];
    const int b = blockIdx.z, i0 = blockIdx.y * 32, d0 = blockIdx.x * 32;
    const int t = threadIdx.x;
    {
        const int il = t >> 3, d4 = t & 7;
        float4 v = *(const float4*)(ctx + ((size_t)b * 2048 + i0 + il) * 512 + d0 + d4 * 4);
        tile[il][d4 * 4 + 0] = v.x; tile[il][d4 * 4 + 1] = v.y;
        tile[il][d4 * 4 + 2] = v.z; tile[il][d4 * 4 + 3] = v.w;
    }
    __syncthreads();
    {
        const int dl = t >> 3, i4 = t & 7;
        ushort4 h, l;
        float v0 = tile[i4 * 4 + 0][dl], v1 = tile[i4 * 4 + 1][dl];
        float v2 = tile[i4 * 4 + 2][dl], v3 = tile[i4 * 4 + 3][dl];
        h.x = f2bf(v0); l.x = f2bf(v0 - bf2f(h.x));
        h.y = f2bf(v1); l.y = f2bf(v1 - bf2f(h.y));
        h.z = f2bf(v2); l.z = f2bf(v2 - bf2f(h.z));
        h.w = f2bf(v3); l.w = f2bf(v3 - bf2f(h.w));
        const size_t o = ((size_t)b * 512 + d0 + dl) * 2048 + i0 + i4 * 4;
        *(ushort4*)(tHi + o) = h;
        *(ushort4*)(tLo + o) = l;
    }
}

// ---------------------------------------------------------------------------
// Scores: attn_raw[b,o,i] = sum_d outp[o,d]*ctx[i,d], split-3 MFMA.
// Block 128x128, BK=32, 4 waves (2x2), wave tile 64x64 = 4x4 MFMA 16x16x32.
// ---------------------------------------------------------------------------
__global__ __launch_bounds__(256) void scores_mfma(
    const unsigned short* __restrict__ Agh, const unsigned short* __restrict__ Agl,
    const unsigned short* __restrict__ Bgh, const unsigned short* __restrict__ Bgl,
    float* __restrict__ attn)
{
    __shared__ __attribute__((aligned(16))) unsigned short Ah[128 * 32], Al[128 * 32],
                                                           Bh[128 * 32], Bl[128 * 32];
    const int b = blockIdx.z, oy = blockIdx.y, ix = blockIdx.x;
    const int tid = threadIdx.x, wave = tid >> 6, lane = tid & 63;
    const int wm = wave >> 1, wn = wave & 1;
    const int c16 = lane & 15, q8 = (lane >> 4) * 8;

    const size_t arow = (size_t)(b * 2048 + oy * 128);
    const size_t brow = (size_t)(b * 2048 + ix * 128);

    f4v acc[4][4];
#pragma unroll
    for (int i = 0; i < 4; ++i)
#pragma unroll
        for (int j = 0; j < 4; ++j) acc[i][j] = (f4v)0.0f;

    for (int kk = 0; kk < 512; kk += 32) {
#pragma unroll
        for (int it = 0; it < 2; ++it) {
            const int r0 = it * 64 + wave * 16;
            const int rr = r0 + (lane >> 2);
            const size_t ga = (arow + rr) * 512 + kk + (lane & 3) * 8;
            const size_t gb = (brow + rr) * 512 + kk + (lane & 3) * 8;
            async16(&Ah[r0 * 32], Agh + ga);
            async16(&Al[r0 * 32], Agl + ga);
            async16(&Bh[r0 * 32], Bgh + gb);
            async16(&Bl[r0 * 32], Bgl + gb);
        }
        __syncthreads();
        s8v ah[4], al[4], bh[4], bl[4];
#pragma unroll
        for (int t = 0; t < 4; ++t) {
            ah[t] = *(const s8v*)&Ah[(wm * 64 + t * 16 + c16) * 32 + q8];
            al[t] = *(const s8v*)&Al[(wm * 64 + t * 16 + c16) * 32 + q8];
            bh[t] = *(const s8v*)&Bh[(wn * 64 + t * 16 + c16) * 32 + q8];
            bl[t] = *(const s8v*)&Bl[(wn * 64 + t * 16 + c16) * 32 + q8];
        }
#pragma unroll
        for (int mt = 0; mt < 4; ++mt)
#pragma unroll
            for (int nt = 0; nt < 4; ++nt) {
                acc[mt][nt] = __builtin_amdgcn_mfma_f32_16x16x32_bf16(ah[mt], bh[nt], acc[mt][nt], 0, 0, 0);
                acc[mt][nt] = __builtin_amdgcn_mfma_f32_16x16x32_bf16(ah[mt], bl[nt], acc[mt][nt], 0, 0, 0);
                acc[mt][nt] = __builtin_amdgcn_mfma_f32_16x16x32_bf16(al[mt], bh[nt], acc[mt][nt], 0, 0, 0);
            }
        __syncthreads();
    }
    // C/D layout: col=lane&15, row=(lane>>4)*4+reg
    float* dst = attn + ((size_t)(b * 2048 + oy * 128 + wm * 64)) * 2048 + ix * 128 + wn * 64;
    const int q4 = (lane >> 4) * 4;
#pragma unroll
    for (int mt = 0; mt < 4; ++mt)
#pragma unroll
        for (int nt = 0; nt < 4; ++nt)
#pragma unroll
            for (int r = 0; r < 4; ++r)
                dst[(size_t)(mt * 16 + q4 + r) * 2048 + nt * 16 + c16] = acc[mt][nt][r];
}

// ---------------------------------------------------------------------------
// Softmax (in-place, one block per 2048-wide row)
// ---------------------------------------------------------------------------
__global__ __launch_bounds__(256) void softmax_kernel(float* __restrict__ attn)
{
    const size_t base = (size_t)blockIdx.x * 2048;
    const int tid = threadIdx.x;
    float4 v0 = *(float4*)(attn + base + tid * 4);
    float4 v1 = *(float4*)(attn + base + 1024 + tid * 4);

    float mx = fmaxf(fmaxf(fmaxf(v0.x, v0.y), fmaxf(v0.z, v0.w)),
                     fmaxf(fmaxf(v1.x, v1.y), fmaxf(v1.z, v1.w)));
#pragma unroll
    for (int off = 32; off > 0; off >>= 1) mx = fmaxf(mx, __shfl_down(mx, off));

    __shared__ float red[4];
    const int wave = tid >> 6, lane = tid & 63;
    if (lane == 0) red[wave] = mx;
    __syncthreads();
    if (tid == 0) red[0] = fmaxf(fmaxf(red[0], red[1]), fmaxf(red[2], red[3]));
    __syncthreads();
    mx = red[0];
    __syncthreads();

    v0.x = expf(v0.x - mx); v0.y = expf(v0.y - mx);
    v0.z = expf(v0.z - mx); v0.w = expf(v0.w - mx);
    v1.x = expf(v1.x - mx); v1.y = expf(v1.y - mx);
    v1.z = expf(v1.z - mx); v1.w = expf(v1.w - mx);

    float s = v0.x + v0.y + v0.z + v0.w + v1.x + v1.y + v1.z + v1.w;
#pragma unroll
    for (int off = 32; off > 0; off >>= 1) s += __shfl_down(s, off);
    if (lane == 0) red[wave] = s;
    __syncthreads();
    if (tid == 0) red[0] = red[0] + red[1] + red[2] + red[3];
    __syncthreads();
    const float inv = 1.0f / red[0];

    v0.x *= inv; v0.y *= inv; v0.z *= inv; v0.w *= inv;
    v1.x *= inv; v1.y *= inv; v1.z *= inv; v1.w *= inv;
    *(float4*)(attn + base + tid * 4) = v0;
    *(float4*)(attn + base + 1024 + tid * 4) = v1;
}

// ---------------------------------------------------------------------------
// PV: mix[b,o,d] = sum_i attn[o,i]*ctxT[d,i]; attn bf16 (inline cvt), ctxT split.
// Epilogue stores mix as hi/lo bf16 for the linear kernel.
// ---------------------------------------------------------------------------
__global__ __launch_bounds__(256) void pv_mfma(
    const float* __restrict__ attn,
    const unsigned short* __restrict__ Bgh, const unsigned short* __restrict__ Bgl,
    unsigned short* __restrict__ mixHi, unsigned short* __restrict__ mixLo)
{
    __shared__ __attribute__((aligned(16))) unsigned short Ab[128 * 32],
                                                           Bh[128 * 32], Bl[128 * 32];
    const int b = blockIdx.z, my = blockIdx.y, nx = blockIdx.x;
    const int tid = threadIdx.x, wave = tid >> 6, lane = tid & 63;
    const int wm = wave >> 1, wn = wave & 1;
    const int c16 = lane & 15, q8 = (lane >> 4) * 8;

    const float* Abase = attn + ((size_t)b * 2048 + my * 128) * 2048;
    const size_t brow = (size_t)(b * 512 + nx * 128);

    f4v acc[4][4];
#pragma unroll
    for (int i = 0; i < 4; ++i)
#pragma unroll
        for (int j = 0; j < 4; ++j) acc[i][j] = (f4v)0.0f;

    for (int kk = 0; kk < 2048; kk += 32) {
#pragma unroll
        for (int it = 0; it < 4; ++it) {           // A: f32 -> bf16 inline
            const int idx = tid + it * 256;
            const int r = idx >> 3, kc = idx & 7;
            float4 v = *(const float4*)(Abase + (size_t)r * 2048 + kk + kc * 4);
            ushort4 h;
            h.x = f2bf(v.x); h.y = f2bf(v.y); h.z = f2bf(v.z); h.w = f2bf(v.w);
            *(ushort4*)&Ab[r * 32 + kc * 4] = h;
        }
#pragma unroll
        for (int it = 0; it < 2; ++it) {           // B: async bf16 staging
            const int r0 = it * 64 + wave * 16;
            const size_t gb = (brow + r0 + (lane >> 2)) * 2048 + kk + (lane & 3) * 8;
            async16(&Bh[r0 * 32], Bgh + gb);
            async16(&Bl[r0 * 32], Bgl + gb);
        }
        __syncthreads();
        s8v ab[4], bh[4], bl[4];
#pragma unroll
        for (int t = 0; t < 4; ++t) {
            ab[t] = *(const s8v*)&Ab[(wm * 64 + t * 16 + c16) * 32 + q8];
            bh[t] = *(const s8v*)&Bh[(wn * 64 + t * 16 + c16) * 32 + q8];
            bl[t] = *(const s8v*)&Bl[(wn * 64 + t * 16 + c16) * 32 + q8];
        }
#pragma unroll
        for (int mt = 0; mt < 4; ++mt)
#pragma unroll
            for (int nt = 0; nt < 4; ++nt) {
                acc[mt][nt] = __builtin_amdgcn_mfma_f32_16x16x32_bf16(ab[mt], bh[nt], acc[mt][nt], 0, 0, 0);
                acc[mt][nt] = __builtin_amdgcn_mfma_f32_16x16x32_bf16(ab[mt], bl[nt], acc[mt][nt], 0, 0, 0);
            }
        __syncthreads();
    }
    const int q4 = (lane >> 4) * 4;
    const size_t mrow = (size_t)(b * 2048 + my * 128 + wm * 64);
#pragma unroll
    for (int mt = 0; mt < 4; ++mt)
#pragma unroll
        for (int nt = 0; nt < 4; ++nt) {
            const int col = nx * 128 + wn * 64 + nt * 16 + c16;
#pragma unroll
            for (int r = 0; r < 4; ++r) {
                float v = acc[mt][nt][r];
                unsigned short h = f2bf(v);
                unsigned short l = f2bf(v - bf2f(h));
                const size_t o = (mrow + mt * 16 + q4 + r) * 512 + col;
                mixHi[o] = h; mixLo[o] = l;
            }
        }
}

// ---------------------------------------------------------------------------
// Linear: out[m,n] = tanh(b[n] + sum_c comb[m,c]*W[n,c]); full split-3.
// comb = [mix | outp] selected by k-offset. M=16384, N=512, K=1024.
// ---------------------------------------------------------------------------
__global__ __launch_bounds__(256) void linear_mfma(
    const unsigned short* __restrict__ mixHi, const unsigned short* __restrict__ mixLo,
    const unsigned short* __restrict__ outHi, const unsigned short* __restrict__ outLo,
    const unsigned short* __restrict__ Wh, const unsigned short* __restrict__ Wl,
    const float* __restrict__ bias, float* __restrict__ dst)
{
    __shared__ __attribute__((aligned(16))) unsigned short Ah[128 * 32], Al[128 * 32],
                                                           Bh[128 * 32], Bl[128 * 32];
    const int my = blockIdx.y, nx = blockIdx.x;
    const int tid = threadIdx.x, wave = tid >> 6, lane = tid & 63;
    const int wm = wave >> 1, wn = wave & 1;
    const int c16 = lane & 15, q8 = (lane >> 4) * 8;

    f4v acc[4][4];
#pragma unroll
    for (int i = 0; i < 4; ++i)
#pragma unroll
        for (int j = 0; j < 4; ++j) acc[i][j] = (f4v)0.0f;

    for (int kk = 0; kk < 1024; kk += 32) {
        const unsigned short* ah_src = (kk < 512) ? mixHi : outHi;
        const unsigned short* al_src = (kk < 512) ? mixLo : outLo;
        const int kc0 = (kk < 512) ? kk : kk - 512;
#pragma unroll
        for (int it = 0; it < 2; ++it) {
            const int r0 = it * 64 + wave * 16;
            const size_t ga = (size_t)(my * 128 + r0 + (lane >> 2)) * 512 + kc0 + (lane & 3) * 8;
            const size_t gb = (size_t)(nx * 128 + r0 + (lane >> 2)) * 1024 + kk + (lane & 3) * 8;
            async16(&Ah[r0 * 32], ah_src + ga);
            async16(&Al[r0 * 32], al_src + ga);
            async16(&Bh[r0 * 32], Wh + gb);
            async16(&Bl[r0 * 32], Wl + gb);
        }
        __syncthreads();
        s8v ah[4], al[4], bh[4], bl[4];
#pragma unroll
        for (int t = 0; t < 4; ++t) {
            ah[t] = *(const s8v*)&Ah[(wm * 64 + t * 16 + c16) * 32 + q8];
            al[t] = *(const s8v*)&Al[(wm * 64 + t * 16 + c16) * 32 + q8];
            bh[t] = *(const s8v*)&Bh[(wn * 64 + t * 16 + c16) * 32 + q8];
            bl[t] = *(const s8v*)&Bl[(wn * 64 + t * 16 + c16) * 32 + q8];
        }
#pragma unroll
        for (int mt = 0; mt < 4; ++mt)
#pragma unroll
            for (int nt = 0; nt < 4; ++nt) {
                acc[mt][nt] = __builtin_amdgcn_mfma_f32_16x16x32_bf16(ah[mt], bh[nt], acc[mt][nt], 0, 0, 0);
                acc[mt][nt] = __builtin_amdgcn_mfma_f32_16x16x32_bf16(ah[mt], bl[nt], acc[mt][nt], 0, 0, 0);
                acc[mt][nt] = __builtin_amdgcn_mfma_f32_16x16x32_bf16(al[mt], bh[nt], acc[mt][nt], 0, 0, 0);
            }
        __syncthreads();
    }
    const int q4 = (lane >> 4) * 4;
#pragma unroll
    for (int mt = 0; mt < 4; ++mt)
#pragma unroll
        for (int nt = 0; nt < 4; ++nt) {
            const int col = nx * 128 + wn * 64 + nt * 16 + c16;
            const float bb = bias[col];
#pragma unroll
            for (int r = 0; r < 4; ++r) {
                const size_t row = (size_t)(my * 128 + wm * 64 + mt * 16 + q4 + r);
                dst[row * 512 + col] = tanhf(acc[mt][nt][r] + bb);
            }
        }
}

// ===========================================================================
// Fallback f32 path (round-0 kernels) — used if ws_size is too small.
// ===========================================================================
#define BK 32
#define PAD 68

__global__ __launch_bounds__(256) void scores_f32(
    const float* __restrict__ outp, const float* __restrict__ ctx,
    float* __restrict__ attn)
{
    __shared__ float As[BK][PAD];
    __shared__ float Bs[BK][PAD];
    const int b = blockIdx.z, oy = blockIdx.y, ix = blockIdx.x;
    const int tid = threadIdx.x;
    const int tx = tid & 15, ty = tid >> 4;
    const float* Abase = outp + ((size_t)b * 2048 + oy * 64) * 512;
    const float* Bbase = ctx  + ((size_t)b * 2048 + ix * 64) * 512;
    float acc[4][4] = {};
    for (int kk = 0; kk < 512; kk += BK) {
#pragma unroll
        for (int h = 0; h < 2; ++h) {
            const int f = tid + h * 256;
            const int row = f >> 3, k4 = f & 7;
            float4 a = *(const float4*)(Abase + (size_t)row * 512 + kk + k4 * 4);
            float4 c = *(const float4*)(Bbase + (size_t)row * 512 + kk + k4 * 4);
            As[k4 * 4 + 0][row] = a.x; As[k4 * 4 + 1][row] = a.y;
            As[k4 * 4 + 2][row] = a.z; As[k4 * 4 + 3][row] = a.w;
            Bs[k4 * 4 + 0][row] = c.x; Bs[k4 * 4 + 1][row] = c.y;
            Bs[k4 * 4 + 2][row] = c.z; Bs[k4 * 4 + 3][row] = c.w;
        }
        __syncthreads();
#pragma unroll
        for (int k = 0; k < BK; ++k) {
            float4 av = *(const float4*)&As[k][ty * 4];
            float4 bv = *(const float4*)&Bs[k][tx * 4];
            acc[0][0] += av.x * bv.x; acc[0][1] += av.x * bv.y; acc[0][2] += av.x * bv.z; acc[0][3] += av.x * bv.w;
            acc[1][0] += av.y * bv.x; acc[1][1] += av.y * bv.y; acc[1][2] += av.y * bv.z; acc[1][3] += av.y * bv.w;
            acc[2][0] += av.z * bv.x; acc[2][1] += av.z * bv.y; acc[2][2] += av.z * bv.z; acc[2][3] += av.z * bv.w;
            acc[3][0] += av.w * bv.x; acc[3][1] += av.w * bv.y; acc[3][2] += av.w * bv.z; acc[3][3] += av.w * bv.w;
        }
        __syncthreads();
    }
    float* dst = attn + ((size_t)b * 2048 + oy * 64 + ty * 4) * 2048 + ix * 64 + tx * 4;
#pragma unroll
    for (int i = 0; i < 4; ++i)
        *(float4*)(dst + (size_t)i * 2048) = make_float4(acc[i][0], acc[i][1], acc[i][2], acc[i][3]);
}

__global__ __launch_bounds__(256) void pv_f32(
    const float* __restrict__ attn, const float* __restrict__ ctx,
    float* __restrict__ mix)
{
    __shared__ float As[BK][PAD];
    __shared__ float Bs[BK][PAD];
    const int b = blockIdx.z, my = blockIdx.y, nx = blockIdx.x;
    const int tid = threadIdx.x;
    const int tx = tid & 15, ty = tid >> 4;
    const float* Abase = attn + ((size_t)b * 2048 + my * 64) * 2048;
    const float* Bbase = ctx  + ((size_t)b * 2048) * 512 + nx * 64;
    float acc[4][4] = {};
    for (int kk = 0; kk < 2048; kk += BK) {
#pragma unroll
        for (int h = 0; h < 2; ++h) {
            const int f = tid + h * 256;
            const int row = f >> 3, k4 = f & 7;
            float4 a = *(const float4*)(Abase + (size_t)row * 2048 + kk + k4 * 4);
            As[k4 * 4 + 0][row] = a.x; As[k4 * 4 + 1][row] = a.y;
            As[k4 * 4 + 2][row] = a.z; As[k4 * 4 + 3][row] = a.w;
            const int krow = f >> 4, col4 = f & 15;
            float4 c = *(const float4*)(Bbase + (size_t)(kk + krow) * 512 + col4 * 4);
            *(float4*)&Bs[krow][col4 * 4] = c;
        }
        __syncthreads();
#pragma unroll
        for (int k = 0; k < BK; ++k) {
            float4 av = *(const float4*)&As[k][ty * 4];
            float4 bv = *(const float4*)&Bs[k][tx * 4];
            acc[0][0] += av.x * bv.x; acc[0][1] += av.x * bv.y; acc[0][2] += av.x * bv.z; acc[0][3] += av.x * bv.w;
            acc[1][0] += av.y * bv.x; acc[1][1] += av.y * bv.y; acc[1][2] += av.y * bv.z; acc[1][3] += av.y * bv.w;
            acc[2][0] += av.z * bv.x; acc[2][1] += av.z * bv.y; acc[2][2] += av.z * bv.z; acc[2][3] += av.z * bv.w;
            acc[3][0] += av.w * bv.x; acc[3][1] += av.w * bv.y; acc[3][2] += av.w * bv.z; acc[3][3] += av.w * bv.w;
        }
        __syncthreads();
    }
    float* dst = mix + ((size_t)b * 2048 + my * 64 + ty * 4) * 512 + nx * 64 + tx * 4;
#pragma unroll
    for (int i = 0; i < 4; ++i)
        *(float4*)(dst + (size_t)i * 512) = make_float4(acc[i][0], acc[i][1], acc[i][2], acc[i][3]);
}

__global__ __launch_bounds__(256) void linear_f32(
    const float* __restrict__ mix, const float* __restrict__ outp,
    const float* __restrict__ Wm, const float* __restrict__ bias,
    float* __restrict__ dst)
{
    __shared__ float As[BK][PAD];
    __shared__ float Ws[BK][PAD];
    const int my = blockIdx.y, nx = blockIdx.x;
    const int tid = threadIdx.x;
    const int tx = tid & 15, ty = tid >> 4;
    const int m0 = my * 64, n0 = nx * 64;
    float acc[4][4] = {};
    for (int kk = 0; kk < 1024; kk += BK) {
        const float* Abase = (kk < 512) ? (mix + (size_t)m0 * 512 + kk)
                                        : (outp + (size_t)m0 * 512 + (kk - 512));
#pragma unroll
        for (int h = 0; h < 2; ++h) {
            const int f = tid + h * 256;
            const int row = f >> 3, k4 = f & 7;
            float4 a = *(const float4*)(Abase + (size_t)row * 512 + k4 * 4);
            As[k4 * 4 + 0][row] = a.x; As[k4 * 4 + 1][row] = a.y;
            As[k4 * 4 + 2][row] = a.z; As[k4 * 4 + 3][row] = a.w;
            float4 w = *(const float4*)(Wm + (size_t)(n0 + row) * 1024 + kk + k4 * 4);
            Ws[k4 * 4 + 0][row] = w.x; Ws[k4 * 4 + 1][row] = w.y;
            Ws[k4 * 4 + 2][row] = w.z; Ws[k4 * 4 + 3][row] = w.w;
        }
        __syncthreads();
#pragma unroll
        for (int k = 0; k < BK; ++k) {
            float4 av = *(const float4*)&As[k][ty * 4];
            float4 bv = *(const float4*)&Ws[k][tx * 4];
            acc[0][0] += av.x * bv.x; acc[0][1] += av.x * bv.y; acc[0][2] += av.x * bv.z; acc[0][3] += av.x * bv.w;
            acc[1][0] += av.y * bv.x; acc[1][1] += av.y * bv.y; acc[1][2] += av.y * bv.z; acc[1][3] += av.y * bv.w;
            acc[2][0] += av.z * bv.x; acc[2][1] += av.z * bv.y; acc[2][2] += av.z * bv.z; acc[2][3] += av.z * bv.w;
            acc[3][0] += av.w * bv.x; acc[3][1] += av.w * bv.y; acc[3][2] += av.w * bv.z; acc[3][3] += av.w * bv.w;
        }
        __syncthreads();
    }
#pragma unroll
    for (int i = 0; i < 4; ++i) {
        const int n = n0 + tx * 4;
        float4 bv = *(const float4*)(bias + n);
        float4 v;
        v.x = tanhf(acc[i][0] + bv.x); v.y = tanhf(acc[i][1] + bv.y);
        v.z = tanhf(acc[i][2] + bv.z); v.w = tanhf(acc[i][3] + bv.w);
        *(float4*)(dst + (size_t)(m0 + ty * 4 + i) * 512 + n) = v;
    }
}

// ===========================================================================
extern "C" void kernel_launch(void* const* d_in, const int* in_sizes, int n_in,
                              void* d_out, int out_size, void* d_ws, size_t ws_size,
                              hipStream_t stream) {
    const float* outp = (const float*)d_in[0];   // [8,2048,512]
    const float* ctx  = (const float*)d_in[1];   // [8,2048,512]
    const float* Wm   = (const float*)d_in[2];   // [512,1024]
    const float* bias = (const float*)d_in[3];   // [512]

    float* out  = (float*)d_out;                 // [8,2048,512]
    float* attn = out + (size_t)8 * 2048 * 512;  // [8,2048,2048]

    const size_t MB = 1ull << 20;
    const size_t NEED = 130 * MB;

    if (ws_size >= NEED) {
        char* w = (char*)d_ws;
        unsigned short* outp_hi = (unsigned short*)(w);
        unsigned short* outp_lo = (unsigned short*)(w + 16 * MB);
        unsigned short* ctx_hi  = (unsigned short*)(w + 32 * MB);
        unsigned short* ctx_lo  = (unsigned short*)(w + 48 * MB);
        unsigned short* ctxT_hi = (unsigned short*)(w + 64 * MB);
        unsigned short* ctxT_lo = (unsigned short*)(w + 80 * MB);
        unsigned short* W_hi    = (unsigned short*)(w + 96 * MB);
        unsigned short* W_lo    = (unsigned short*)(w + 97 * MB);
        unsigned short* mix_hi  = (unsigned short*)(w + 98 * MB);
        unsigned short* mix_lo  = (unsigned short*)(w + 114 * MB);

        split_kernel<<<dim3(8192), 256, 0, stream>>>(outp, outp_hi, outp_lo);
        split_kernel<<<dim3(8192), 256, 0, stream>>>(ctx, ctx_hi, ctx_lo);
        split_kernel<<<dim3(512), 256, 0, stream>>>(Wm, W_hi, W_lo);
        transpose_split_kernel<<<dim3(16, 64, 8), 256, 0, stream>>>(ctx, ctxT_hi, ctxT_lo);

        scores_mfma<<<dim3(16, 16, 8), 256, 0, stream>>>(outp_hi, outp_lo, ctx_hi, ctx_lo, attn);
        softmax_kernel<<<dim3(16384), 256, 0, stream>>>(attn);
        pv_mfma<<<dim3(4, 16, 8), 256, 0, stream>>>(attn, ctxT_hi, ctxT_lo, mix_hi, mix_lo);
        linear_mfma<<<dim3(4, 128), 256, 0, stream>>>(mix_hi, mix_lo, outp_hi, outp_lo,
                                                      W_hi, W_lo, bias, out);
    } else {
        float* mix = (float*)d_ws;
        scores_f32<<<dim3(32, 32, 8), 256, 0, stream>>>(outp, ctx, attn);
        softmax_kernel<<<dim3(16384), 256, 0, stream>>>(attn);
        pv_f32<<<dim3(8, 32, 8), 256, 0, stream>>>(attn, ctx, mix);
        linear_f32<<<dim3(8, 256), 256, 0, stream>>>(mix, outp, Wm, bias, out);
    }
}

// Round 3
// 533.479 us; speedup vs baseline: 2.6412x; 1.0782x over previous
//
#include <hip/hip_runtime.h>
#include <math.h>

// B=8, T_OUT=2048, T_IN=2048, D=512
// attn = softmax(outp @ ctx^T); mix = attn @ ctx; out = tanh([mix,outp] @ W^T + b)
// d_out = out (8.4M f32) ++ attn (33.6M f32)
//
// bf16 hi/lo split-MFMA emulation of f32 GEMMs (no fp32 MFMA on CDNA4).
//   scores: 3-MFMA split; pv: bf16 attn x split ctxT (2 MFMA); linear: 3-MFMA.
// This round: XCD swizzle (b=id&7 -> per-XCD L2 tile residency), softmax
// emits bf16 attn so pv stages A via global_load_lds (no inline VALU cvt).

typedef short s8v __attribute__((ext_vector_type(8)));    // 8 bf16 (4 VGPR)
typedef float f4v __attribute__((ext_vector_type(4)));    // MFMA acc

__device__ __forceinline__ unsigned short f2bf(float f) {
    unsigned int u = __float_as_uint(f);
    u += 0x7fff + ((u >> 16) & 1);           // RNE
    return (unsigned short)(u >> 16);
}
__device__ __forceinline__ float bf2f(unsigned short h) {
    return __uint_as_float(((unsigned int)h) << 16);
}

__device__ __forceinline__ void async16(void* lds, const void* g) {
    __builtin_amdgcn_global_load_lds(
        (const __attribute__((address_space(1))) unsigned int*)g,
        (__attribute__((address_space(3))) unsigned int*)lds, 16, 0, 0);
}

// ---------------------------------------------------------------------------
// Prep: elementwise f32 -> bf16 hi/lo split
// ---------------------------------------------------------------------------
__global__ __launch_bounds__(256) void split_kernel(
    const float* __restrict__ src, unsigned short* __restrict__ hi,
    unsigned short* __restrict__ lo)
{
    const size_t i = ((size_t)blockIdx.x * 256 + threadIdx.x) * 4;
    float4 v = *(const float4*)(src + i);
    ushort4 h, l;
    h.x = f2bf(v.x); l.x = f2bf(v.x - bf2f(h.x));
    h.y = f2bf(v.y); l.y = f2bf(v.y - bf2f(h.y));
    h.z = f2bf(v.z); l.z = f2bf(v.z - bf2f(h.z));
    h.w = f2bf(v.w); l.w = f2bf(v.w - bf2f(h.w));
    *(ushort4*)(hi + i) = h;
    *(ushort4*)(lo + i) = l;
}

// ---------------------------------------------------------------------------
// Prep: ctx[b][i][d] f32 -> ctxT_hi/lo[b][d][i] bf16
// ---------------------------------------------------------------------------
__global__ __launch_bounds__(256) void transpose_split_kernel(
    const float* __restrict__ ctx, unsigned short* __restrict__ tHi,
    unsigned short* __restrict__ tLo)
{
    __shared__ float tile[32][33];
    const int b = blockIdx.z, i0 = blockIdx.y * 32, d0 = blockIdx.x * 32;
    const int t = threadIdx.x;
    {
        const int il = t >> 3, d4 = t & 7;
        float4 v = *(const float4*)(ctx + ((size_t)b * 2048 + i0 + il) * 512 + d0 + d4 * 4);
        tile[il][d4 * 4 + 0] = v.x; tile[il][d4 * 4 + 1] = v.y;
        tile[il][d4 * 4 + 2] = v.z; tile[il][d4 * 4 + 3] = v.w;
    }
    __syncthreads();
    {
        const int dl = t >> 3, i4 = t & 7;
        ushort4 h, l;
        float v0 = tile[i4 * 4 + 0][dl], v1 = tile[i4 * 4 + 1][dl];
        float v2 = tile[i4 * 4 + 2][dl], v3 = tile[i4 * 4 + 3][dl];
        h.x = f2bf(v0); l.x = f2bf(v0 - bf2f(h.x));
        h.y = f2bf(v1); l.y = f2bf(v1 - bf2f(h.y));
        h.z = f2bf(v2); l.z = f2bf(v2 - bf2f(h.z));
        h.w = f2bf(v3); l.w = f2bf(v3 - bf2f(h.w));
        const size_t o = ((size_t)b * 512 + d0 + dl) * 2048 + i0 + i4 * 4;
        *(ushort4*)(tHi + o) = h;
        *(ushort4*)(tLo + o) = l;
    }
}

// ---------------------------------------------------------------------------
// Scores: split-3 MFMA, 128x128 tile. 1D grid 2048, b=id&7 (XCD pinning),
// ix inner (A-tile L2 reuse, B-set 4MB resident in the XCD's L2).
// ---------------------------------------------------------------------------
__global__ __launch_bounds__(256) void scores_mfma(
    const unsigned short* __restrict__ Agh, const unsigned short* __restrict__ Agl,
    const unsigned short* __restrict__ Bgh, const unsigned short* __restrict__ Bgl,
    float* __restrict__ attn)
{
    __shared__ __attribute__((aligned(16))) unsigned short Ah[128 * 32], Al[128 * 32],
                                                           Bh[128 * 32], Bl[128 * 32];
    const int id = blockIdx.x;
    const int b = id & 7, seq = id >> 3;
    const int ix = seq & 15, oy = seq >> 4;
    const int tid = threadIdx.x, wave = tid >> 6, lane = tid & 63;
    const int wm = wave >> 1, wn = wave & 1;
    const int c16 = lane & 15, q8 = (lane >> 4) * 8;

    const size_t arow = (size_t)(b * 2048 + oy * 128);
    const size_t brow = (size_t)(b * 2048 + ix * 128);

    f4v acc[4][4];
#pragma unroll
    for (int i = 0; i < 4; ++i)
#pragma unroll
        for (int j = 0; j < 4; ++j) acc[i][j] = (f4v)0.0f;

    for (int kk = 0; kk < 512; kk += 32) {
#pragma unroll
        for (int it = 0; it < 2; ++it) {
            const int r0 = it * 64 + wave * 16;
            const int rr = r0 + (lane >> 2);
            const size_t ga = (arow + rr) * 512 + kk + (lane & 3) * 8;
            const size_t gb = (brow + rr) * 512 + kk + (lane & 3) * 8;
            async16(&Ah[r0 * 32], Agh + ga);
            async16(&Al[r0 * 32], Agl + ga);
            async16(&Bh[r0 * 32], Bgh + gb);
            async16(&Bl[r0 * 32], Bgl + gb);
        }
        __syncthreads();
        s8v ah[4], al[4], bh[4], bl[4];
#pragma unroll
        for (int t = 0; t < 4; ++t) {
            ah[t] = *(const s8v*)&Ah[(wm * 64 + t * 16 + c16) * 32 + q8];
            al[t] = *(const s8v*)&Al[(wm * 64 + t * 16 + c16) * 32 + q8];
            bh[t] = *(const s8v*)&Bh[(wn * 64 + t * 16 + c16) * 32 + q8];
            bl[t] = *(const s8v*)&Bl[(wn * 64 + t * 16 + c16) * 32 + q8];
        }
#pragma unroll
        for (int mt = 0; mt < 4; ++mt)
#pragma unroll
            for (int nt = 0; nt < 4; ++nt) {
                acc[mt][nt] = __builtin_amdgcn_mfma_f32_16x16x32_bf16(ah[mt], bh[nt], acc[mt][nt], 0, 0, 0);
                acc[mt][nt] = __builtin_amdgcn_mfma_f32_16x16x32_bf16(ah[mt], bl[nt], acc[mt][nt], 0, 0, 0);
                acc[mt][nt] = __builtin_amdgcn_mfma_f32_16x16x32_bf16(al[mt], bh[nt], acc[mt][nt], 0, 0, 0);
            }
        __syncthreads();
    }
    float* dst = attn + ((size_t)(b * 2048 + oy * 128 + wm * 64)) * 2048 + ix * 128 + wn * 64;
    const int q4 = (lane >> 4) * 4;
#pragma unroll
    for (int mt = 0; mt < 4; ++mt)
#pragma unroll
        for (int nt = 0; nt < 4; ++nt)
#pragma unroll
            for (int r = 0; r < 4; ++r)
                dst[(size_t)(mt * 16 + q4 + r) * 2048 + nt * 16 + c16] = acc[mt][nt][r];
}

// ---------------------------------------------------------------------------
// Softmax: in-place; optionally emits bf16 copy of the final probabilities.
// ---------------------------------------------------------------------------
__global__ __launch_bounds__(256) void softmax_kernel(
    float* __restrict__ attn, unsigned short* __restrict__ attn_bf)
{
    const size_t base = (size_t)blockIdx.x * 2048;
    const int tid = threadIdx.x;
    float4 v0 = *(float4*)(attn + base + tid * 4);
    float4 v1 = *(float4*)(attn + base + 1024 + tid * 4);

    float mx = fmaxf(fmaxf(fmaxf(v0.x, v0.y), fmaxf(v0.z, v0.w)),
                     fmaxf(fmaxf(v1.x, v1.y), fmaxf(v1.z, v1.w)));
#pragma unroll
    for (int off = 32; off > 0; off >>= 1) mx = fmaxf(mx, __shfl_down(mx, off));

    __shared__ float red[4];
    const int wave = tid >> 6, lane = tid & 63;
    if (lane == 0) red[wave] = mx;
    __syncthreads();
    if (tid == 0) red[0] = fmaxf(fmaxf(red[0], red[1]), fmaxf(red[2], red[3]));
    __syncthreads();
    mx = red[0];
    __syncthreads();

    v0.x = expf(v0.x - mx); v0.y = expf(v0.y - mx);
    v0.z = expf(v0.z - mx); v0.w = expf(v0.w - mx);
    v1.x = expf(v1.x - mx); v1.y = expf(v1.y - mx);
    v1.z = expf(v1.z - mx); v1.w = expf(v1.w - mx);

    float s = v0.x + v0.y + v0.z + v0.w + v1.x + v1.y + v1.z + v1.w;
#pragma unroll
    for (int off = 32; off > 0; off >>= 1) s += __shfl_down(s, off);
    if (lane == 0) red[wave] = s;
    __syncthreads();
    if (tid == 0) red[0] = red[0] + red[1] + red[2] + red[3];
    __syncthreads();
    const float inv = 1.0f / red[0];

    v0.x *= inv; v0.y *= inv; v0.z *= inv; v0.w *= inv;
    v1.x *= inv; v1.y *= inv; v1.z *= inv; v1.w *= inv;
    *(float4*)(attn + base + tid * 4) = v0;
    *(float4*)(attn + base + 1024 + tid * 4) = v1;

    if (attn_bf) {
        ushort4 h0, h1;
        h0.x = f2bf(v0.x); h0.y = f2bf(v0.y); h0.z = f2bf(v0.z); h0.w = f2bf(v0.w);
        h1.x = f2bf(v1.x); h1.y = f2bf(v1.y); h1.z = f2bf(v1.z); h1.w = f2bf(v1.w);
        *(ushort4*)(attn_bf + base + tid * 4) = h0;
        *(ushort4*)(attn_bf + base + 1024 + tid * 4) = h1;
    }
}

// ---------------------------------------------------------------------------
// PV tier-1: A = attn_bf (async staged), B = ctxT hi/lo (2 MFMA).
// 1D grid 512: b=id&7, nx inner. Writes mix as bf16 hi/lo.
// ---------------------------------------------------------------------------
__global__ __launch_bounds__(256) void pv_mfma_bf(
    const unsigned short* __restrict__ attn_bf,
    const unsigned short* __restrict__ Bgh, const unsigned short* __restrict__ Bgl,
    unsigned short* __restrict__ mixHi, unsigned short* __restrict__ mixLo)
{
    __shared__ __attribute__((aligned(16))) unsigned short Ab[128 * 32],
                                                           Bh[128 * 32], Bl[128 * 32];
    const int id = blockIdx.x;
    const int b = id & 7, seq = id >> 3;
    const int nx = seq & 3, my = seq >> 2;
    const int tid = threadIdx.x, wave = tid >> 6, lane = tid & 63;
    const int wm = wave >> 1, wn = wave & 1;
    const int c16 = lane & 15, q8 = (lane >> 4) * 8;

    const size_t arow = (size_t)(b * 2048 + my * 128);
    const size_t brow = (size_t)(b * 512 + nx * 128);

    f4v acc[4][4];
#pragma unroll
    for (int i = 0; i < 4; ++i)
#pragma unroll
        for (int j = 0; j < 4; ++j) acc[i][j] = (f4v)0.0f;

    for (int kk = 0; kk < 2048; kk += 32) {
#pragma unroll
        for (int it = 0; it < 2; ++it) {
            const int r0 = it * 64 + wave * 16;
            const int rr = r0 + (lane >> 2);
            const size_t ga = (arow + rr) * 2048 + kk + (lane & 3) * 8;
            const size_t gb = (brow + rr) * 2048 + kk + (lane & 3) * 8;
            async16(&Ab[r0 * 32], attn_bf + ga);
            async16(&Bh[r0 * 32], Bgh + gb);
            async16(&Bl[r0 * 32], Bgl + gb);
        }
        __syncthreads();
        s8v ab[4], bh[4], bl[4];
#pragma unroll
        for (int t = 0; t < 4; ++t) {
            ab[t] = *(const s8v*)&Ab[(wm * 64 + t * 16 + c16) * 32 + q8];
            bh[t] = *(const s8v*)&Bh[(wn * 64 + t * 16 + c16) * 32 + q8];
            bl[t] = *(const s8v*)&Bl[(wn * 64 + t * 16 + c16) * 32 + q8];
        }
#pragma unroll
        for (int mt = 0; mt < 4; ++mt)
#pragma unroll
            for (int nt = 0; nt < 4; ++nt) {
                acc[mt][nt] = __builtin_amdgcn_mfma_f32_16x16x32_bf16(ab[mt], bh[nt], acc[mt][nt], 0, 0, 0);
                acc[mt][nt] = __builtin_amdgcn_mfma_f32_16x16x32_bf16(ab[mt], bl[nt], acc[mt][nt], 0, 0, 0);
            }
        __syncthreads();
    }
    const int q4 = (lane >> 4) * 4;
    const size_t mrow = (size_t)(b * 2048 + my * 128 + wm * 64);
#pragma unroll
    for (int mt = 0; mt < 4; ++mt)
#pragma unroll
        for (int nt = 0; nt < 4; ++nt) {
            const int col = nx * 128 + wn * 64 + nt * 16 + c16;
#pragma unroll
            for (int r = 0; r < 4; ++r) {
                float v = acc[mt][nt][r];
                unsigned short h = f2bf(v);
                unsigned short l = f2bf(v - bf2f(h));
                const size_t o = (mrow + mt * 16 + q4 + r) * 512 + col;
                mixHi[o] = h; mixLo[o] = l;
            }
        }
}

// ---------------------------------------------------------------------------
// PV tier-2 (round-1 structure + swizzle): A = f32 attn converted inline.
// ---------------------------------------------------------------------------
__global__ __launch_bounds__(256) void pv_mfma_cvt(
    const float* __restrict__ attn,
    const unsigned short* __restrict__ Bgh, const unsigned short* __restrict__ Bgl,
    unsigned short* __restrict__ mixHi, unsigned short* __restrict__ mixLo)
{
    __shared__ __attribute__((aligned(16))) unsigned short Ab[128 * 32],
                                                           Bh[128 * 32], Bl[128 * 32];
    const int id = blockIdx.x;
    const int b = id & 7, seq = id >> 3;
    const int nx = seq & 3, my = seq >> 2;
    const int tid = threadIdx.x, wave = tid >> 6, lane = tid & 63;
    const int wm = wave >> 1, wn = wave & 1;
    const int c16 = lane & 15, q8 = (lane >> 4) * 8;

    const float* Abase = attn + ((size_t)b * 2048 + my * 128) * 2048;
    const size_t brow = (size_t)(b * 512 + nx * 128);

    f4v acc[4][4];
#pragma unroll
    for (int i = 0; i < 4; ++i)
#pragma unroll
        for (int j = 0; j < 4; ++j) acc[i][j] = (f4v)0.0f;

    for (int kk = 0; kk < 2048; kk += 32) {
#pragma unroll
        for (int it = 0; it < 4; ++it) {
            const int idx = tid + it * 256;
            const int r = idx >> 3, kc = idx & 7;
            float4 v = *(const float4*)(Abase + (size_t)r * 2048 + kk + kc * 4);
            ushort4 h;
            h.x = f2bf(v.x); h.y = f2bf(v.y); h.z = f2bf(v.z); h.w = f2bf(v.w);
            *(ushort4*)&Ab[r * 32 + kc * 4] = h;
        }
#pragma unroll
        for (int it = 0; it < 2; ++it) {
            const int r0 = it * 64 + wave * 16;
            const size_t gb = (brow + r0 + (lane >> 2)) * 2048 + kk + (lane & 3) * 8;
            async16(&Bh[r0 * 32], Bgh + gb);
            async16(&Bl[r0 * 32], Bgl + gb);
        }
        __syncthreads();
        s8v ab[4], bh[4], bl[4];
#pragma unroll
        for (int t = 0; t < 4; ++t) {
            ab[t] = *(const s8v*)&Ab[(wm * 64 + t * 16 + c16) * 32 + q8];
            bh[t] = *(const s8v*)&Bh[(wn * 64 + t * 16 + c16) * 32 + q8];
            bl[t] = *(const s8v*)&Bl[(wn * 64 + t * 16 + c16) * 32 + q8];
        }
#pragma unroll
        for (int mt = 0; mt < 4; ++mt)
#pragma unroll
            for (int nt = 0; nt < 4; ++nt) {
                acc[mt][nt] = __builtin_amdgcn_mfma_f32_16x16x32_bf16(ab[mt], bh[nt], acc[mt][nt], 0, 0, 0);
                acc[mt][nt] = __builtin_amdgcn_mfma_f32_16x16x32_bf16(ab[mt], bl[nt], acc[mt][nt], 0, 0, 0);
            }
        __syncthreads();
    }
    const int q4 = (lane >> 4) * 4;
    const size_t mrow = (size_t)(b * 2048 + my * 128 + wm * 64);
#pragma unroll
    for (int mt = 0; mt < 4; ++mt)
#pragma unroll
        for (int nt = 0; nt < 4; ++nt) {
            const int col = nx * 128 + wn * 64 + nt * 16 + c16;
#pragma unroll
            for (int r = 0; r < 4; ++r) {
                float v = acc[mt][nt][r];
                unsigned short h = f2bf(v);
                unsigned short l = f2bf(v - bf2f(h));
                const size_t o = (mrow + mt * 16 + q4 + r) * 512 + col;
                mixHi[o] = h; mixLo[o] = l;
            }
        }
}

// ---------------------------------------------------------------------------
// Linear: full split-3, fused bias+tanh. 1D grid 512:
// xcd=id&7 -> my%8, nx inner per-XCD (A tile fetched once, W set L2-resident)
// ---------------------------------------------------------------------------
__global__ __launch_bounds__(256) void linear_mfma(
    const unsigned short* __restrict__ mixHi, const unsigned short* __restrict__ mixLo,
    const unsigned short* __restrict__ outHi, const unsigned short* __restrict__ outLo,
    const unsigned short* __restrict__ Wh, const unsigned short* __restrict__ Wl,
    const float* __restrict__ bias, float* __restrict__ dst)
{
    __shared__ __attribute__((aligned(16))) unsigned short Ah[128 * 32], Al[128 * 32],
                                                           Bh[128 * 32], Bl[128 * 32];
    const int id = blockIdx.x;
    const int xcd = id & 7, seq = id >> 3;
    const int nx = seq & 3;
    const int my = (seq >> 2) * 8 + xcd;
    const int tid = threadIdx.x, wave = tid >> 6, lane = tid & 63;
    const int wm = wave >> 1, wn = wave & 1;
    const int c16 = lane & 15, q8 = (lane >> 4) * 8;

    f4v acc[4][4];
#pragma unroll
    for (int i = 0; i < 4; ++i)
#pragma unroll
        for (int j = 0; j < 4; ++j) acc[i][j] = (f4v)0.0f;

    for (int kk = 0; kk < 1024; kk += 32) {
        const unsigned short* ah_src = (kk < 512) ? mixHi : outHi;
        const unsigned short* al_src = (kk < 512) ? mixLo : outLo;
        const int kc0 = (kk < 512) ? kk : kk - 512;
#pragma unroll
        for (int it = 0; it < 2; ++it) {
            const int r0 = it * 64 + wave * 16;
            const size_t ga = (size_t)(my * 128 + r0 + (lane >> 2)) * 512 + kc0 + (lane & 3) * 8;
            const size_t gb = (size_t)(nx * 128 + r0 + (lane >> 2)) * 1024 + kk + (lane & 3) * 8;
            async16(&Ah[r0 * 32], ah_src + ga);
            async16(&Al[r0 * 32], al_src + ga);
            async16(&Bh[r0 * 32], Wh + gb);
            async16(&Bl[r0 * 32], Wl + gb);
        }
        __syncthreads();
        s8v ah[4], al[4], bh[4], bl[4];
#pragma unroll
        for (int t = 0; t < 4; ++t) {
            ah[t] = *(const s8v*)&Ah[(wm * 64 + t * 16 + c16) * 32 + q8];
            al[t] = *(const s8v*)&Al[(wm * 64 + t * 16 + c16) * 32 + q8];
            bh[t] = *(const s8v*)&Bh[(wn * 64 + t * 16 + c16) * 32 + q8];
            bl[t] = *(const s8v*)&Bl[(wn * 64 + t * 16 + c16) * 32 + q8];
        }
#pragma unroll
        for (int mt = 0; mt < 4; ++mt)
#pragma unroll
            for (int nt = 0; nt < 4; ++nt) {
                acc[mt][nt] = __builtin_amdgcn_mfma_f32_16x16x32_bf16(ah[mt], bh[nt], acc[mt][nt], 0, 0, 0);
                acc[mt][nt] = __builtin_amdgcn_mfma_f32_16x16x32_bf16(ah[mt], bl[nt], acc[mt][nt], 0, 0, 0);
                acc[mt][nt] = __builtin_amdgcn_mfma_f32_16x16x32_bf16(al[mt], bh[nt], acc[mt][nt], 0, 0, 0);
            }
        __syncthreads();
    }
    const int q4 = (lane >> 4) * 4;
#pragma unroll
    for (int mt = 0; mt < 4; ++mt)
#pragma unroll
        for (int nt = 0; nt < 4; ++nt) {
            const int col = nx * 128 + wn * 64 + nt * 16 + c16;
            const float bb = bias[col];
#pragma unroll
            for (int r = 0; r < 4; ++r) {
                const size_t row = (size_t)(my * 128 + wm * 64 + mt * 16 + q4 + r);
                dst[row * 512 + col] = tanhf(acc[mt][nt][r] + bb);
            }
        }
}

// ===========================================================================
// Fallback f32 path
// ===========================================================================
#define BK 32
#define PAD 68

__global__ __launch_bounds__(256) void scores_f32(
    const float* __restrict__ outp, const float* __restrict__ ctx,
    float* __restrict__ attn)
{
    __shared__ float As[BK][PAD];
    __shared__ float Bs[BK][PAD];
    const int b = blockIdx.z, oy = blockIdx.y, ix = blockIdx.x;
    const int tid = threadIdx.x;
    const int tx = tid & 15, ty = tid >> 4;
    const float* Abase = outp + ((size_t)b * 2048 + oy * 64) * 512;
    const float* Bbase = ctx  + ((size_t)b * 2048 + ix * 64) * 512;
    float acc[4][4] = {};
    for (int kk = 0; kk < 512; kk += BK) {
#pragma unroll
        for (int h = 0; h < 2; ++h) {
            const int f = tid + h * 256;
            const int row = f >> 3, k4 = f & 7;
            float4 a = *(const float4*)(Abase + (size_t)row * 512 + kk + k4 * 4);
            float4 c = *(const float4*)(Bbase + (size_t)row * 512 + kk + k4 * 4);
            As[k4 * 4 + 0][row] = a.x; As[k4 * 4 + 1][row] = a.y;
            As[k4 * 4 + 2][row] = a.z; As[k4 * 4 + 3][row] = a.w;
            Bs[k4 * 4 + 0][row] = c.x; Bs[k4 * 4 + 1][row] = c.y;
            Bs[k4 * 4 + 2][row] = c.z; Bs[k4 * 4 + 3][row] = c.w;
        }
        __syncthreads();
#pragma unroll
        for (int k = 0; k < BK; ++k) {
            float4 av = *(const float4*)&As[k][ty * 4];
            float4 bv = *(const float4*)&Bs[k][tx * 4];
            acc[0][0] += av.x * bv.x; acc[0][1] += av.x * bv.y; acc[0][2] += av.x * bv.z; acc[0][3] += av.x * bv.w;
            acc[1][0] += av.y * bv.x; acc[1][1] += av.y * bv.y; acc[1][2] += av.y * bv.z; acc[1][3] += av.y * bv.w;
            acc[2][0] += av.z * bv.x; acc[2][1] += av.z * bv.y; acc[2][2] += av.z * bv.z; acc[2][3] += av.z * bv.w;
            acc[3][0] += av.w * bv.x; acc[3][1] += av.w * bv.y; acc[3][2] += av.w * bv.z; acc[3][3] += av.w * bv.w;
        }
        __syncthreads();
    }
    float* dst = attn + ((size_t)b * 2048 + oy * 64 + ty * 4) * 2048 + ix * 64 + tx * 4;
#pragma unroll
    for (int i = 0; i < 4; ++i)
        *(float4*)(dst + (size_t)i * 2048) = make_float4(acc[i][0], acc[i][1], acc[i][2], acc[i][3]);
}

__global__ __launch_bounds__(256) void pv_f32(
    const float* __restrict__ attn, const float* __restrict__ ctx,
    float* __restrict__ mix)
{
    __shared__ float As[BK][PAD];
    __shared__ float Bs[BK][PAD];
    const int b = blockIdx.z, my = blockIdx.y, nx = blockIdx.x;
    const int tid = threadIdx.x;
    const int tx = tid & 15, ty = tid >> 4;
    const float* Abase = attn + ((size_t)b * 2048 + my * 64) * 2048;
    const float* Bbase = ctx  + ((size_t)b * 2048) * 512 + nx * 64;
    float acc[4][4] = {};
    for (int kk = 0; kk < 2048; kk += BK) {
#pragma unroll
        for (int h = 0; h < 2; ++h) {
            const int f = tid + h * 256;
            const int row = f >> 3, k4 = f & 7;
            float4 a = *(const float4*)(Abase + (size_t)row * 2048 + kk + k4 * 4);
            As[k4 * 4 + 0][row] = a.x; As[k4 * 4 + 1][row] = a.y;
            As[k4 * 4 + 2][row] = a.z; As[k4 * 4 + 3][row] = a.w;
            const int krow = f >> 4, col4 = f & 15;
            float4 c = *(const float4*)(Bbase + (size_t)(kk + krow) * 512 + col4 * 4);
            *(float4*)&Bs[krow][col4 * 4] = c;
        }
        __syncthreads();
#pragma unroll
        for (int k = 0; k < BK; ++k) {
            float4 av = *(const float4*)&As[k][ty * 4];
            float4 bv = *(const float4*)&Bs[k][tx * 4];
            acc[0][0] += av.x * bv.x; acc[0][1] += av.x * bv.y; acc[0][2] += av.x * bv.z; acc[0][3] += av.x * bv.w;
            acc[1][0] += av.y * bv.x; acc[1][1] += av.y * bv.y; acc[1][2] += av.y * bv.z; acc[1][3] += av.y * bv.w;
            acc[2][0] += av.z * bv.x; acc[2][1] += av.z * bv.y; acc[2][2] += av.z * bv.z; acc[2][3] += av.z * bv.w;
            acc[3][0] += av.w * bv.x; acc[3][1] += av.w * bv.y; acc[3][2] += av.w * bv.z; acc[3][3] += av.w * bv.w;
        }
        __syncthreads();
    }
    float* dst = mix + ((size_t)b * 2048 + my * 64 + ty * 4) * 512 + nx * 64 + tx * 4;
#pragma unroll
    for (int i = 0; i < 4; ++i)
        *(float4*)(dst + (size_t)i * 512) = make_float4(acc[i][0], acc[i][1], acc[i][2], acc[i][3]);
}

__global__ __launch_bounds__(256) void linear_f32(
    const float* __restrict__ mix, const float* __restrict__ outp,
    const float* __restrict__ Wm, const float* __restrict__ bias,
    float* __restrict__ dst)
{
    __shared__ float As[BK][PAD];
    __shared__ float Ws[BK][PAD];
    const int my = blockIdx.y, nx = blockIdx.x;
    const int tid = threadIdx.x;
    const int tx = tid & 15, ty = tid >> 4;
    const int m0 = my * 64, n0 = nx * 64;
    float acc[4][4] = {};
    for (int kk = 0; kk < 1024; kk += BK) {
        const float* Abase = (kk < 512) ? (mix + (size_t)m0 * 512 + kk)
                                        : (outp + (size_t)m0 * 512 + (kk - 512));
#pragma unroll
        for (int h = 0; h < 2; ++h) {
            const int f = tid + h * 256;
            const int row = f >> 3, k4 = f & 7;
            float4 a = *(const float4*)(Abase + (size_t)row * 512 + k4 * 4);
            As[k4 * 4 + 0][row] = a.x; As[k4 * 4 + 1][row] = a.y;
            As[k4 * 4 + 2][row] = a.z; As[k4 * 4 + 3][row] = a.w;
            float4 w = *(const float4*)(Wm + (size_t)(n0 + row) * 1024 + kk + k4 * 4);
            Ws[k4 * 4 + 0][row] = w.x; Ws[k4 * 4 + 1][row] = w.y;
            Ws[k4 * 4 + 2][row] = w.z; Ws[k4 * 4 + 3][row] = w.w;
        }
        __syncthreads();
#pragma unroll
        for (int k = 0; k < BK; ++k) {
            float4 av = *(const float4*)&As[k][ty * 4];
            float4 bv = *(const float4*)&Ws[k][tx * 4];
            acc[0][0] += av.x * bv.x; acc[0][1] += av.x * bv.y; acc[0][2] += av.x * bv.z; acc[0][3] += av.x * bv.w;
            acc[1][0] += av.y * bv.x; acc[1][1] += av.y * bv.y; acc[1][2] += av.y * bv.z; acc[1][3] += av.y * bv.w;
            acc[2][0] += av.z * bv.x; acc[2][1] += av.z * bv.y; acc[2][2] += av.z * bv.z; acc[2][3] += av.z * bv.w;
            acc[3][0] += av.w * bv.x; acc[3][1] += av.w * bv.y; acc[3][2] += av.w * bv.z; acc[3][3] += av.w * bv.w;
        }
        __syncthreads();
    }
#pragma unroll
    for (int i = 0; i < 4; ++i) {
        const int n = n0 + tx * 4;
        float4 bv = *(const float4*)(bias + n);
        float4 v;
        v.x = tanhf(acc[i][0] + bv.x); v.y = tanhf(acc[i][1] + bv.y);
        v.z = tanhf(acc[i][2] + bv.z); v.w = tanhf(acc[i][3] + bv.w);
        *(float4*)(dst + (size_t)(m0 + ty * 4 + i) * 512 + n) = v;
    }
}

// ===========================================================================
extern "C" void kernel_launch(void* const* d_in, const int* in_sizes, int n_in,
                              void* d_out, int out_size, void* d_ws, size_t ws_size,
                              hipStream_t stream) {
    const float* outp = (const float*)d_in[0];   // [8,2048,512]
    const float* ctx  = (const float*)d_in[1];   // [8,2048,512]
    const float* Wm   = (const float*)d_in[2];   // [512,1024]
    const float* bias = (const float*)d_in[3];   // [512]

    float* out  = (float*)d_out;
    float* attn = out + (size_t)8 * 2048 * 512;

    const size_t MB = 1ull << 20;
    const size_t NEED1 = 162 * MB;   // tier-1: +64MB attn_bf, mix aliases ctx
    const size_t NEED2 = 130 * MB;   // tier-2: round-1 layout

    if (ws_size >= NEED1) {
        char* w = (char*)d_ws;
        unsigned short* outp_hi = (unsigned short*)(w);              // 16MB
        unsigned short* outp_lo = (unsigned short*)(w + 16 * MB);
        unsigned short* ctx_hi  = (unsigned short*)(w + 32 * MB);
        unsigned short* ctx_lo  = (unsigned short*)(w + 48 * MB);
        unsigned short* ctxT_hi = (unsigned short*)(w + 64 * MB);
        unsigned short* ctxT_lo = (unsigned short*)(w + 80 * MB);
        unsigned short* W_hi    = (unsigned short*)(w + 96 * MB);
        unsigned short* W_lo    = (unsigned short*)(w + 97 * MB);
        unsigned short* attn_bf = (unsigned short*)(w + 98 * MB);    // 64MB
        // mix aliases ctx_hi/ctx_lo (ctx dead after scores)
        unsigned short* mix_hi  = ctx_hi;
        unsigned short* mix_lo  = ctx_lo;

        split_kernel<<<dim3(8192), 256, 0, stream>>>(outp, outp_hi, outp_lo);
        split_kernel<<<dim3(8192), 256, 0, stream>>>(ctx, ctx_hi, ctx_lo);
        split_kernel<<<dim3(512), 256, 0, stream>>>(Wm, W_hi, W_lo);
        transpose_split_kernel<<<dim3(16, 64, 8), 256, 0, stream>>>(ctx, ctxT_hi, ctxT_lo);

        scores_mfma<<<dim3(2048), 256, 0, stream>>>(outp_hi, outp_lo, ctx_hi, ctx_lo, attn);
        softmax_kernel<<<dim3(16384), 256, 0, stream>>>(attn, attn_bf);
        pv_mfma_bf<<<dim3(512), 256, 0, stream>>>(attn_bf, ctxT_hi, ctxT_lo, mix_hi, mix_lo);
        linear_mfma<<<dim3(512), 256, 0, stream>>>(mix_hi, mix_lo, outp_hi, outp_lo,
                                                   W_hi, W_lo, bias, out);
    } else if (ws_size >= NEED2) {
        char* w = (char*)d_ws;
        unsigned short* outp_hi = (unsigned short*)(w);
        unsigned short* outp_lo = (unsigned short*)(w + 16 * MB);
        unsigned short* ctx_hi  = (unsigned short*)(w + 32 * MB);
        unsigned short* ctx_lo  = (unsigned short*)(w + 48 * MB);
        unsigned short* ctxT_hi = (unsigned short*)(w + 64 * MB);
        unsigned short* ctxT_lo = (unsigned short*)(w + 80 * MB);
        unsigned short* W_hi    = (unsigned short*)(w + 96 * MB);
        unsigned short* W_lo    = (unsigned short*)(w + 97 * MB);
        unsigned short* mix_hi  = (unsigned short*)(w + 98 * MB);
        unsigned short* mix_lo  = (unsigned short*)(w + 114 * MB);

        split_kernel<<<dim3(8192), 256, 0, stream>>>(outp, outp_hi, outp_lo);
        split_kernel<<<dim3(8192), 256, 0, stream>>>(ctx, ctx_hi, ctx_lo);
        split_kernel<<<dim3(512), 256, 0, stream>>>(Wm, W_hi, W_lo);
        transpose_split_kernel<<<dim3(16, 64, 8), 256, 0, stream>>>(ctx, ctxT_hi, ctxT_lo);

        scores_mfma<<<dim3(2048), 256, 0, stream>>>(outp_hi, outp_lo, ctx_hi, ctx_lo, attn);
        softmax_kernel<<<dim3(16384), 256, 0, stream>>>(attn, nullptr);
        pv_mfma_cvt<<<dim3(512), 256, 0, stream>>>(attn, ctxT_hi, ctxT_lo, mix_hi, mix_lo);
        linear_mfma<<<dim3(512), 256, 0, stream>>>(mix_hi, mix_lo, outp_hi, outp_lo,
                                                   W_hi, W_lo, bias, out);
    } else {
        float* mix = (float*)d_ws;
        scores_f32<<<dim3(32, 32, 8), 256, 0, stream>>>(outp, ctx, attn);
        softmax_kernel<<<dim3(16384), 256, 0, stream>>>(attn, nullptr);
        pv_f32<<<dim3(8, 32, 8), 256, 0, stream>>>(attn, ctx, mix);
        linear_f32<<<dim3(8, 256), 256, 0, stream>>>(mix, outp, Wm, bias, out);
    }
}